// Round 5
// baseline (522.791 us; speedup 1.0000x reference)
//
#include <hip/hip_runtime.h>
#include <math.h>

#define NROWS  16384   // B*S
#define DMODEL 1024
#define NHEAD  16
#define HDIM   64
#define SEQ    4096
#define NBATCH 4
#define NBH    64      // NBATCH*NHEAD
#define SCHUNK 16      // split-K chunks over S for kv aggregation
#define W1     2097152u   // one split weight matrix [1024][2048] in ushorts

typedef __attribute__((ext_vector_type(8))) short bf16x8;
typedef __attribute__((ext_vector_type(4))) float f32x4;

__device__ __forceinline__ unsigned short f2bf(float f) {
    unsigned u = __float_as_uint(f);
    u += 0x7FFFu + ((u >> 16) & 1u);   // round-to-nearest-even
    return (unsigned short)(u >> 16);
}
__device__ __forceinline__ float bf2f(unsigned short h) {
    return __uint_as_float((unsigned)h << 16);
}

__device__ __forceinline__ void gload16(const void* g, void* l) {
    __builtin_amdgcn_global_load_lds(
        (const __attribute__((address_space(1))) unsigned int*)g,
        (__attribute__((address_space(3))) unsigned int*)l, 16, 0, 0);
}

// ---------------------------------------------------------------------------
// split x [M][1024] f32 -> xs [M][2048] bf16 (cols 0-1023 = hi, 1024-2047 = lo)
// ---------------------------------------------------------------------------
__global__ __launch_bounds__(256)
void split_x(const float* __restrict__ a, unsigned short* __restrict__ dst)
{
    const int idx = blockIdx.x * 256 + threadIdx.x;   // over M*1024/4
    const int row = idx >> 8;
    const int c4  = (idx & 255) * 4;
    const float4 v = ((const float4*)a)[idx];
    ushort4 H, L;
    H.x = f2bf(v.x); L.x = f2bf(v.x - bf2f(H.x));
    H.y = f2bf(v.y); L.y = f2bf(v.y - bf2f(H.y));
    H.z = f2bf(v.z); L.z = f2bf(v.z - bf2f(H.z));
    H.w = f2bf(v.w); L.w = f2bf(v.w - bf2f(H.w));
    *(ushort4*)&dst[(size_t)row * 2048 + c4]        = H;
    *(ushort4*)&dst[(size_t)row * 2048 + 1024 + c4] = L;
}

// all 4 weight matrices -> [y][1024][2048] bf16 hi|lo (y: 0=Wq 1=Wk 2=Wv 3=Wo)
__global__ __launch_bounds__(256)
void split_w4(const float* __restrict__ a0, const float* __restrict__ a1,
              const float* __restrict__ a2, const float* __restrict__ a3,
              unsigned short* __restrict__ dst)
{
    const int y = blockIdx.y;
    const float* src = (y == 0) ? a0 : (y == 1) ? a1 : (y == 2) ? a2 : a3;
    unsigned short* d = dst + (size_t)y * W1;
    const int idx = blockIdx.x * 256 + threadIdx.x;   // over 1024*1024/4
    const int row = idx >> 8;
    const int c4  = (idx & 255) * 4;
    const float4 v = ((const float4*)src)[idx];
    ushort4 H, L;
    H.x = f2bf(v.x); L.x = f2bf(v.x - bf2f(H.x));
    H.y = f2bf(v.y); L.y = f2bf(v.y - bf2f(H.y));
    H.z = f2bf(v.z); L.z = f2bf(v.z - bf2f(H.z));
    H.w = f2bf(v.w); L.w = f2bf(v.w - bf2f(H.w));
    *(ushort4*)&d[(size_t)row * 2048 + c4]        = H;
    *(ushort4*)&d[(size_t)row * 2048 + 1024 + c4] = L;
}

// ---------------------------------------------------------------------------
// Split GEMM as ONE bf16 GEMM with concatenated K=3072: terms [hh | hl | lh].
//   A-col = k<1024 ? k : k-1024   over xs  [M][2048] = [xh|xl]
//   B-col = k<2048 ? k : k-2048   over Ws  [N][2048] = [Wh|Wl]
// 256x256 tile, BK=64, 8 waves (2Mx4N), per-wave 128x64. LDS dbuf 2x64KiB,
// A[256][64] + B[256][64] bf16 per buffer. XOR swizzle: 16B slot ^= (row&7)
// on BOTH sides (pre-swizzled global source for gload16, swizzled ds_read)
// -> conflict-free frag reads. 4 phases/K-tile, raw barriers, setprio on
// MFMA, prefetch in phases 0-2 stays in flight, one vmcnt0 handoff per tile.
// ---------------------------------------------------------------------------
template<int ELU>
__global__ __launch_bounds__(512)
void gemm_c3(const unsigned short* __restrict__ A2, const unsigned short* __restrict__ W2,
             const float* __restrict__ bias, float* __restrict__ C)
{
    __shared__ unsigned short lds[65536];   // 2 buf x (A 16384 + B 16384) ushorts
    const int t    = threadIdx.x;
    const int lane = t & 63;
    const int wv   = t >> 6;        // wave 0..7
    const int wr   = wv >> 2;       // M half    0..1  (128 rows)
    const int wcn  = wv & 3;        // N quarter 0..3  (64 cols)

    // XCD swizzle (bijective, 256 blocks): 8 m-panels x 4 n per XCD
    const int bid  = blockIdx.x;
    const int swz  = ((bid & 7) << 5) | (bid >> 3);
    const int am0  = (swz >> 2) * 256;     // A panel row base
    const int bn0  = (swz & 3) * 256;      // W panel row base (= C col base)

    const int fr   = lane & 15;            // frag row
    const int j0   = lane >> 4;            // frag k-slot 0..3
    const int fx   = lane & 7;             // = row&7 for swizzled frag reads
    const int srow8 = lane >> 3;           // staging: row within 8-row chunk
    const int sslot = (lane & 7) ^ srow8;  // staging: pre-swizzled source slot

    f32x4 acc[8][4];
#pragma unroll
    for (int i = 0; i < 8; ++i)
#pragma unroll
        for (int j = 0; j < 4; ++j)
#pragma unroll
            for (int e = 0; e < 4; ++e) acc[i][j][e] = 0.f;

    // stage quarter q (0,1 = A halves; 2,3 = B halves) of K-tile kt into buffer wbU
    auto stageQ = [&](int q, int kt, unsigned wbU) {
        const int k0 = kt * 64;
        const bool isA = (q < 2);
        const int kb  = isA ? ((k0 < 1024) ? k0 : k0 - 1024)
                            : ((k0 < 2048) ? k0 : k0 - 2048);
        const unsigned short* src = isA ? A2 : W2;
        const int rb0 = (isA ? am0 : bn0) + (q & 1) * 128;
        const unsigned ldsT = wbU + (isA ? 0u : 16384u) + (unsigned)((q & 1) * 128) * 64u;
#pragma unroll
        for (int c = 0; c < 2; ++c) {
            const int r = rb0 + wv * 16 + c * 8 + srow8;                 // 8-row-aligned chunk
            gload16(src + (size_t)r * 2048 + kb + sslot * 8,
                    (unsigned short*)&lds[ldsT + (unsigned)(wv * 16 + c * 8) * 64u]);
        }
    };

    // prologue: stage K-tile 0 into buffer 0
#pragma unroll
    for (int q = 0; q < 4; ++q) stageQ(q, 0, 0u);
    __syncthreads();

    for (int kt = 0; kt < 48; ++kt) {
        const unsigned rbU = (kt & 1) ? 32768u : 0u;
        const unsigned wbU = rbU ^ 32768u;
        const bool pf = (kt < 47);

        bf16x8 bfr[2][4];
#pragma unroll
        for (int p = 0; p < 4; ++p) {
            if (p == 0) {
#pragma unroll
                for (int h = 0; h < 2; ++h)
#pragma unroll
                    for (int j = 0; j < 4; ++j) {
                        const unsigned phys = (unsigned)((h * 4 + j0) ^ fx);
                        bfr[h][j] = *(const bf16x8*)&lds[rbU + 16384u +
                            (unsigned)(wcn * 64 + j * 16 + fr) * 64u + phys * 8u];
                    }
            }
            bf16x8 afr[2][2];
#pragma unroll
            for (int i2 = 0; i2 < 2; ++i2) {
                const unsigned ar = (unsigned)(wr * 128 + (p * 2 + i2) * 16 + fr);
#pragma unroll
                for (int h = 0; h < 2; ++h) {
                    const unsigned phys = (unsigned)((h * 4 + j0) ^ fx);
                    afr[i2][h] = *(const bf16x8*)&lds[rbU + ar * 64u + phys * 8u];
                }
            }
            // prefetch: all issued by phase 2 so the handoff drain is cheap
            if (pf) {
                if (p == 0) { stageQ(0, kt + 1, wbU); stageQ(1, kt + 1, wbU); }
                else if (p == 1) stageQ(2, kt + 1, wbU);
                else if (p == 2) stageQ(3, kt + 1, wbU);
            }
            __builtin_amdgcn_s_barrier();
            __builtin_amdgcn_s_setprio(1);
#pragma unroll
            for (int i2 = 0; i2 < 2; ++i2)
#pragma unroll
                for (int j = 0; j < 4; ++j)
#pragma unroll
                    for (int h = 0; h < 2; ++h)
                        acc[p * 2 + i2][j] = __builtin_amdgcn_mfma_f32_16x16x32_bf16(
                            afr[i2][h], bfr[h][j], acc[p * 2 + i2][j], 0, 0, 0);
            __builtin_amdgcn_s_setprio(0);
            if (p < 3) __builtin_amdgcn_s_barrier();
        }
        __syncthreads();   // vmcnt(0) drain + barrier: buffer handoff (once per K-tile)
    }

    // epilogue: C/D layout col=lane&15, row=(lane>>4)*4+reg
    const int crow0 = am0 + wr * 128 + (lane >> 4) * 4;
    const int ccol0 = bn0 + wcn * 64 + fr;
#pragma unroll
    for (int j = 0; j < 4; ++j) {
        const int col = ccol0 + j * 16;
        const float bv = bias[col];
#pragma unroll
        for (int i = 0; i < 8; ++i) {
            const int row = crow0 + i * 16;
#pragma unroll
            for (int r = 0; r < 4; ++r) {
                float v = acc[i][j][r] + bv;
                if (ELU) v = (v > 0.f) ? (v + 1.f) : __expf(v);  // elu(v)+1
                C[(size_t)(row + r) * DMODEL + col] = v;
            }
        }
    }
}

// ---------------------------------------------------------------------------
// kv partials: for (b,h,sc): kvp[d][e] = sum_{s in chunk} k[s,d]*v[s,e],
// ksp[d] = sum k[s,d]. Deterministic split-K, no atomics.
// ---------------------------------------------------------------------------
__global__ __launch_bounds__(512)
void kv_partial(const float* __restrict__ k, const float* __restrict__ v,
                float* __restrict__ kvp, float* __restrict__ ksp)
{
    __shared__ float Ks[32][64];
    __shared__ float Vs[32][64];
    const int t  = threadIdx.x;
    const int bh = blockIdx.x;
    const int b  = bh >> 4;
    const int h  = bh & 15;
    const int sc = blockIdx.y;
    const int d  = t & 63;
    const int e0 = (t >> 6) * 8;

    float acc[8];
#pragma unroll
    for (int j = 0; j < 8; ++j) acc[j] = 0.f;
    float ks = 0.f;

    const size_t rowbase = (size_t)b * SEQ;
    const int sbeg = sc * (SEQ / SCHUNK);       // 256 rows per chunk
    const int send = sbeg + (SEQ / SCHUNK);
    const int lrow = t >> 4;                    // staging: 0..31
    const int lc4  = (t & 15) * 4;

    for (int s0 = sbeg; s0 < send; s0 += 32) {
        const size_t g = (rowbase + s0 + lrow) * DMODEL + h * HDIM + lc4;
        *(float4*)&Ks[lrow][lc4] = *(const float4*)&k[g];
        *(float4*)&Vs[lrow][lc4] = *(const float4*)&v[g];
        __syncthreads();
#pragma unroll 8
        for (int sp = 0; sp < 32; ++sp) {
            const float kd = Ks[sp][d];
            if (t < 64) ks += Ks[sp][t];        // wave 0 only (wave-uniform branch)
            const float4 v0 = *(const float4*)&Vs[sp][e0 + 0];
            const float4 v1 = *(const float4*)&Vs[sp][e0 + 4];
            acc[0] = fmaf(kd, v0.x, acc[0]);  acc[1] = fmaf(kd, v0.y, acc[1]);
            acc[2] = fmaf(kd, v0.z, acc[2]);  acc[3] = fmaf(kd, v0.w, acc[3]);
            acc[4] = fmaf(kd, v1.x, acc[4]);  acc[5] = fmaf(kd, v1.y, acc[5]);
            acc[6] = fmaf(kd, v1.z, acc[6]);  acc[7] = fmaf(kd, v1.w, acc[7]);
        }
        __syncthreads();
    }

    const size_t base = ((size_t)sc * NBH + bh) * HDIM;
    float4 o0; o0.x = acc[0]; o0.y = acc[1]; o0.z = acc[2]; o0.w = acc[3];
    float4 o1; o1.x = acc[4]; o1.y = acc[5]; o1.z = acc[6]; o1.w = acc[7];
    *(float4*)&kvp[(base + d) * HDIM + e0 + 0] = o0;
    *(float4*)&kvp[(base + d) * HDIM + e0 + 4] = o1;
    if (t < 64) ksp[base + t] = ks;
}

__global__ __launch_bounds__(256)
void kv_reduce(const float* __restrict__ kvp, const float* __restrict__ ksp,
               float* __restrict__ kv, float* __restrict__ ksum)
{
    const int i = blockIdx.x * 256 + threadIdx.x;
    const int NKV = NBH * HDIM * HDIM;
    if (i < NKV) {
        float s = 0.f;
#pragma unroll
        for (int c = 0; c < SCHUNK; ++c) s += kvp[(size_t)c * NKV + i];
        kv[i] = s;
    }
    if (i < NBH * HDIM) {
        float s = 0.f;
#pragma unroll
        for (int c = 0; c < SCHUNK; ++c) s += ksp[(size_t)c * NBH * HDIM + i];
        ksum[i] = s;
    }
}

// ---------------------------------------------------------------------------
// att[s,e] = (sum_d q[s,d]*kv[d,e]) / (sum_d q[s,d]*ksum[d] + 1e-6),
// written directly as bf16 hi/lo into the [M][2048] concat layout.
// ---------------------------------------------------------------------------
__global__ __launch_bounds__(256)
void qkv_norm(const float* __restrict__ q, const float* __restrict__ kv,
              const float* __restrict__ ksum, unsigned short* __restrict__ att)
{
    __shared__ float Qs[64][68];
    __shared__ float KVs[64][64];
    __shared__ float kss[64];
    const int t  = threadIdx.x;
    const int s0 = blockIdx.x * 64;
    const int b  = blockIdx.y;
    const int h  = blockIdx.z;
    const int bh = b * NHEAD + h;

#pragma unroll
    for (int i = 0; i < 4; ++i) {
        const int idx = i * 256 + t;
        const int row = idx >> 4;
        const int c4  = (idx & 15) * 4;
        const float4 vq = *(const float4*)&q[((size_t)b * SEQ + s0 + row) * DMODEL + h * HDIM + c4];
        *(float4*)&Qs[row][c4] = vq;
        *(float4*)&((float*)KVs)[idx * 4] = *(const float4*)&kv[(size_t)bh * HDIM * HDIM + idx * 4];
    }
    if (t < 64) kss[t] = ksum[(size_t)bh * HDIM + t];
    __syncthreads();

    const int r  = t >> 2;
    const int e0 = (t & 3) * 16;
    float out[16];
#pragma unroll
    for (int j = 0; j < 16; ++j) out[j] = 0.f;
    float nrm = 0.f;

#pragma unroll 8
    for (int d = 0; d < 64; ++d) {
        const float qd = Qs[r][d];
        nrm = fmaf(qd, kss[d], nrm);
        const float4 k0 = *(const float4*)&KVs[d][e0 + 0];
        const float4 k1 = *(const float4*)&KVs[d][e0 + 4];
        const float4 k2 = *(const float4*)&KVs[d][e0 + 8];
        const float4 k3 = *(const float4*)&KVs[d][e0 + 12];
        out[0]  = fmaf(qd, k0.x, out[0]);  out[1]  = fmaf(qd, k0.y, out[1]);
        out[2]  = fmaf(qd, k0.z, out[2]);  out[3]  = fmaf(qd, k0.w, out[3]);
        out[4]  = fmaf(qd, k1.x, out[4]);  out[5]  = fmaf(qd, k1.y, out[5]);
        out[6]  = fmaf(qd, k1.z, out[6]);  out[7]  = fmaf(qd, k1.w, out[7]);
        out[8]  = fmaf(qd, k2.x, out[8]);  out[9]  = fmaf(qd, k2.y, out[9]);
        out[10] = fmaf(qd, k2.z, out[10]); out[11] = fmaf(qd, k2.w, out[11]);
        out[12] = fmaf(qd, k3.x, out[12]); out[13] = fmaf(qd, k3.y, out[13]);
        out[14] = fmaf(qd, k3.z, out[14]); out[15] = fmaf(qd, k3.w, out[15]);
    }

    const float inv = 1.f / (nrm + 1e-6f);
    const size_t gb = ((size_t)b * SEQ + s0 + r) * 2048 + h * HDIM + e0;
#pragma unroll
    for (int g4 = 0; g4 < 4; ++g4) {
        ushort4 H, L;
        const float v0 = out[g4*4+0] * inv;
        const float v1 = out[g4*4+1] * inv;
        const float v2 = out[g4*4+2] * inv;
        const float v3 = out[g4*4+3] * inv;
        H.x = f2bf(v0); L.x = f2bf(v0 - bf2f(H.x));
        H.y = f2bf(v1); L.y = f2bf(v1 - bf2f(H.y));
        H.z = f2bf(v2); L.z = f2bf(v2 - bf2f(H.z));
        H.w = f2bf(v3); L.w = f2bf(v3 - bf2f(H.w));
        *(ushort4*)&att[gb + g4 * 4]        = H;
        *(ushort4*)&att[gb + 1024 + g4 * 4] = L;
    }
}

// ---------------------------------------------------------------------------
extern "C" void kernel_launch(void* const* d_in, const int* in_sizes, int n_in,
                              void* d_out, int out_size, void* d_ws, size_t ws_size,
                              hipStream_t stream)
{
    const float* x  = (const float*)d_in[0];
    const float* Wq = (const float*)d_in[1];
    const float* bq = (const float*)d_in[2];
    const float* Wk = (const float*)d_in[3];
    const float* bk = (const float*)d_in[4];
    const float* Wv = (const float*)d_in[5];
    const float* bv = (const float*)d_in[6];
    const float* Wo = (const float*)d_in[7];
    const float* bo = (const float*)d_in[8];

    // workspace layout (~153 MB):
    unsigned short* xs  = (unsigned short*)d_ws;                   // [16384][2048] = [xh|xl], later att
    unsigned short* wsp = xs + (size_t)NROWS * 2048;               // 4 x [1024][2048] = [Wh|Wl] per matrix
    float* buf0 = (float*)(wsp + 4u * W1);                         // k, then q (fp32)
    float* kv   = buf0 + (size_t)NROWS * DMODEL;                   // [NBH][64][64]
    float* ksum = kv + NBH * HDIM * HDIM;                          // [NBH][64]
    float* kvp  = ksum + NBH * HDIM;                               // [SCHUNK][NBH][64][64]
    float* ksp  = kvp + (size_t)SCHUNK * NBH * HDIM * HDIM;        // [SCHUNK][NBH][64]
    float* vbuf = (float*)d_out;                                   // v lives in d_out (dead before final GEMM)

    const dim3 gg(256);   // (16384/256) x (1024/256) = 64 x 4, flat + XCD swizzle

    // convert weights + x to bf16 hi/lo concat layouts
    split_w4<<<dim3(1024, 4), 256, 0, stream>>>(Wq, Wk, Wv, Wo, wsp);
    split_x<<<16384, 256, 0, stream>>>(x, xs);
    // k = elu(x@Wk^T + bk)+1 ; v = x@Wv^T + bv
    gemm_c3<1><<<gg, 512, 0, stream>>>(xs, wsp + 1u * W1, bk, buf0);
    gemm_c3<0><<<gg, 512, 0, stream>>>(xs, wsp + 2u * W1, bv, vbuf);
    // kv, ksum (deterministic split-K + reduce)
    kv_partial<<<dim3(NBH, SCHUNK), 512, 0, stream>>>(buf0, vbuf, kvp, ksp);
    kv_reduce<<<1024, 256, 0, stream>>>(kvp, ksp, kv, ksum);
    // q = elu(x@Wq^T + bq)+1   (overwrites k)
    gemm_c3<1><<<gg, 512, 0, stream>>>(xs, wsp, bq, buf0);
    // att = (q@kv)/(q@ksum + 1e-6), fused hi/lo split into xs (x is dead)
    qkv_norm<<<dim3(SEQ / 64, NBATCH, NHEAD), 256, 0, stream>>>(buf0, kv, ksum, xs);
    // out = att@Wo^T + bo  (overwrites v in d_out)
    gemm_c3<0><<<gg, 512, 0, stream>>>(xs, wsp + 3u * W1, bo, (float*)d_out);
}